// Round 16
// baseline (952.542 us; speedup 1.0000x reference)
//
#include <hip/hip_runtime.h>
#include <hip/hip_bf16.h>
#include <math.h>

#define NN   50000
#define EE   800000
#define RREL 16
#define LLAY 5
#define NBINS (NN * RREL)
#define HCAP 565248   // compact rows: ~506k rel cells + pad + 50048 root rows

typedef __attribute__((ext_vector_type(8))) short s8v;
typedef __attribute__((ext_vector_type(4))) float f4v;

__device__ __forceinline__ unsigned short f2bf(float f) {
  __hip_bfloat16 h = __float2bfloat16(f);
  return __builtin_bit_cast(unsigned short, h);
}
__device__ __forceinline__ float bf2f(unsigned int u) {
  return __builtin_bit_cast(float, u << 16);
}
__device__ __forceinline__ void split1(float v, unsigned short& h, unsigned short& l) {
  __hip_bfloat16 hb = __float2bfloat16(v);
  float hf = __bfloat162float(hb);
  h = __builtin_bit_cast(unsigned short, hb);
  __hip_bfloat16 lb = __float2bfloat16(v - hf);
  l = __builtin_bit_cast(unsigned short, lb);
}

// ---------------- build xh0 = bf16([obj_emb[objs] | attr_emb[attributes]]) ----------------
__global__ void build_x0_kernel(const int* __restrict__ objs, const int* __restrict__ attrs,
                                const float* __restrict__ obj_emb, const float* __restrict__ attr_emb,
                                unsigned short* __restrict__ xh) {
  int t = blockIdx.x * blockDim.x + threadIdx.x;
  if (t >= NN * 32) return;
  int n = t >> 5, q = t & 31;
  float4 v;
  if (q < 24) v = *(const float4*)&obj_emb[(size_t)objs[n] * 96 + q * 4];
  else        v = *(const float4*)&attr_emb[(size_t)attrs[n] * 32 + (q - 24) * 4];
  ushort4 h;
  h.x = f2bf(v.x); h.y = f2bf(v.y); h.z = f2bf(v.z); h.w = f2bf(v.w);
  *(ushort4*)&xh[(size_t)n * 128 + q * 4] = h;
}

// ---------------- bf16-convert z (N,128) and attr_emb[attrs] (N,32) ----------------
__global__ void prep_zattr(const float* __restrict__ z, const int* __restrict__ attrs,
                           const float* __restrict__ attr_emb,
                           unsigned short* __restrict__ zh, unsigned short* __restrict__ ah) {
  int t = blockIdx.x * blockDim.x + threadIdx.x;
  if (t >= NN * 40) return;
  int n = t / 40, q = t % 40;
  float4 v;
  ushort4 h;
  if (q < 32) {
    v = *(const float4*)&z[(size_t)n * 128 + q * 4];
    h.x = f2bf(v.x); h.y = f2bf(v.y); h.z = f2bf(v.z); h.w = f2bf(v.w);
    *(ushort4*)&zh[(size_t)n * 128 + q * 4] = h;
  } else {
    int qq = q - 32;
    v = *(const float4*)&attr_emb[(size_t)attrs[n] * 32 + qq * 4];
    h.x = f2bf(v.x); h.y = f2bf(v.y); h.z = f2bf(v.z); h.w = f2bf(v.w);
    *(ushort4*)&ah[(size_t)n * 32 + qq * 4] = h;
  }
}

// ---------------- fused (o,p) count + (s,p) mark ----------------
__global__ void count_mark(const int* __restrict__ triples, int* __restrict__ cnt,
                           int* __restrict__ sMark) {
  int e = blockIdx.x * 256 + threadIdx.x;
  if (e >= EE) return;
  int s = triples[e * 3 + 0], p = triples[e * 3 + 1], o = triples[e * 3 + 2];
  atomicAdd(&cnt[o * RREL + p], 1);
  atomicAdd(&sMark[s * RREL + p], 1);
}
__global__ void scanA(const int* __restrict__ cnt, int* __restrict__ binStart,
                      int* __restrict__ partial) {
  __shared__ int buf[1024];
  int g = blockIdx.x * 1024 + threadIdx.x;
  int v = (g < NBINS) ? cnt[g] : 0;
  buf[threadIdx.x] = v;
  __syncthreads();
  for (int d = 1; d < 1024; d <<= 1) {
    int t = (threadIdx.x >= d) ? buf[threadIdx.x - d] : 0;
    __syncthreads();
    buf[threadIdx.x] += t;
    __syncthreads();
  }
  if (g < NBINS) binStart[g] = buf[threadIdx.x] - v;
  if (threadIdx.x == 1023) partial[blockIdx.x] = buf[1023];
}
__global__ void scanB(int* __restrict__ partial, int* __restrict__ binStart, int nPart) {
  __shared__ int buf[1024];
  int v = (threadIdx.x < nPart) ? partial[threadIdx.x] : 0;
  buf[threadIdx.x] = v;
  __syncthreads();
  for (int d = 1; d < 1024; d <<= 1) {
    int t = (threadIdx.x >= d) ? buf[threadIdx.x - d] : 0;
    __syncthreads();
    buf[threadIdx.x] += t;
    __syncthreads();
  }
  if (threadIdx.x < nPart) partial[threadIdx.x] = buf[threadIdx.x] - v;
  if (threadIdx.x == 1023) binStart[NBINS] = buf[1023];
}
__global__ void scanC(int* __restrict__ binStart, const int* __restrict__ partial) {
  int g = blockIdx.x * 1024 + threadIdx.x;
  if (g < NBINS) binStart[g] += partial[blockIdx.x];
}

// ---------------- (s,p) compaction ----------------
__global__ void count_dp(const int* __restrict__ sMark, int* __restrict__ Dp) {
  __shared__ int lh[RREL];
  if (threadIdx.x < RREL) lh[threadIdx.x] = 0;
  __syncthreads();
  int c = blockIdx.x * 256 + threadIdx.x;
  if (c < NBINS && sMark[c] > 0) atomicAdd(&lh[c & 15], 1);
  __syncthreads();
  if (threadIdx.x < RREL && lh[threadIdx.x] > 0)
    atomicAdd(&Dp[threadIdx.x], lh[threadIdx.x]);
}
// pStart[0..16] = 16 relation partitions + root partition (NN rows); pStart[17] = total
__global__ void pad_scan(const int* __restrict__ Dp, int* __restrict__ pStart) {
  if (threadIdx.x == 0 && blockIdx.x == 0) {
    int s = 0;
    for (int p = 0; p < RREL; ++p) {
      pStart[p] = s;
      s += ((Dp[p] + 127) >> 7) << 7;
    }
    pStart[RREL] = s;                       // root partition base
    s += ((NN + 127) >> 7) << 7;
    pStart[RREL + 1] = s;
  }
}
// spRel[cid] = s*32 + p  (p in 0..15 relation cell, p==16 root row)
__global__ void assign_cells(int* __restrict__ sMark, const int* __restrict__ pStart,
                             int* __restrict__ pcur, int* __restrict__ spRel) {
  __shared__ int lh[RREL], lbase[RREL];
  if (threadIdx.x < RREL) lh[threadIdx.x] = 0;
  __syncthreads();
  int c = blockIdx.x * 256 + threadIdx.x;
  bool occ = (c < NBINS) && (sMark[c] > 0);
  int p = 0, my = 0;
  if (occ) { p = c & 15; my = atomicAdd(&lh[p], 1); }
  __syncthreads();
  if (threadIdx.x < RREL)
    lbase[threadIdx.x] = (lh[threadIdx.x] > 0)
                           ? atomicAdd(&pcur[threadIdx.x], lh[threadIdx.x]) : 0;
  __syncthreads();
  if (occ) {
    int cid = pStart[p] + lbase[p] + my;
    if (cid < HCAP) spRel[cid] = (c >> 4) * 32 + p;
    sMark[c] = cid + 1;
  }
}
__global__ void fill_root(const int* __restrict__ pStart, int* __restrict__ spRel) {
  int n = blockIdx.x * 256 + threadIdx.x;
  if (n >= NN) return;
  int cid = pStart[RREL] + n;
  if (cid < HCAP) spRel[cid] = n * 32 + 16;
}
// offD = cid*128 (element offset into compact H); wD = 1/deg(o,p)
__global__ void place_kernel(const int* __restrict__ triples, const int* __restrict__ cnt,
                             const int* __restrict__ binStart, int* __restrict__ cursor,
                             const int* __restrict__ sMark,
                             int* __restrict__ offD, float* __restrict__ wD) {
  int e = blockIdx.x * 256 + threadIdx.x;
  if (e >= EE) return;
  int s = triples[e * 3 + 0], p = triples[e * 3 + 1], o = triples[e * 3 + 2];
  int bin = o * RREL + p;
  int pos = binStart[bin] + atomicAdd(&cursor[bin], 1);
  int cid = sMark[s * RREL + p] - 1;
  offD[pos] = cid * 128;
  wD[pos] = 1.0f / (float)cnt[bin];
}

// ---------------- weight preps ----------------
__global__ void prep_wrel(const float* __restrict__ Wrel, unsigned short* __restrict__ WT) {
  int t = blockIdx.x * 256 + threadIdx.x;
  if (t >= LLAY * RREL * 128 * 128) return;
  int f = t & 127, k = (t >> 7) & 127, lr = t >> 14;
  float v = Wrel[((size_t)lr * 128 + k) * 128 + f];
  WT[((size_t)lr * 128 + f) * 128 + k] = f2bf(v);
}
__global__ void prep_wroot(const float* __restrict__ Wroot, unsigned short* __restrict__ WT) {
  int t = blockIdx.x * 256 + threadIdx.x;
  if (t >= LLAY * 128 * 128) return;
  int f = t & 127, k = (t >> 7) & 127, l = t >> 14;
  float v = Wroot[((size_t)l * 128 + k) * 128 + f];
  WT[((size_t)l * 128 + f) * 128 + k] = f2bf(v);
}
__global__ void prep_wcat(const float* __restrict__ box_W1, const float* __restrict__ ang_W1,
                          unsigned short* __restrict__ WT) {
  int t = blockIdx.x * 256 + threadIdx.x;
  if (t >= 1024 * 288) return;
  int k = t % 288, c = t / 288;
  float v;
  if (c < 512) v = box_W1[(size_t)k * 512 + c];
  else         v = (k < 256) ? ang_W1[(size_t)k * 512 + (c - 512)] : 0.f;
  WT[(size_t)c * 288 + k] = f2bf(v);
}
__global__ void prep_bcat(const float* __restrict__ box_b1, const float* __restrict__ ang_b1,
                          float* __restrict__ bcat) {
  int t = blockIdx.x * 256 + threadIdx.x;
  if (t >= 1024) return;
  bcat[t] = (t < 512) ? box_b1[t] : ang_b1[t - 512];
}
__global__ void prep_w2cat(const float* __restrict__ box_W2, const float* __restrict__ ang_W2,
                           unsigned short* __restrict__ hi, unsigned short* __restrict__ lo) {
  int t = blockIdx.x * 256 + threadIdx.x;
  if (t >= 32 * 1024) return;
  int k = t & 1023, c = t >> 10;
  float v = 0.f;
  if (c < 6)       { if (k < 512)  v = box_W2[(size_t)k * 6 + c]; }
  else if (c < 30) { if (k >= 512) v = ang_W2[(size_t)(k - 512) * 24 + (c - 6)]; }
  split1(v, hi[(size_t)c * 1024 + k], lo[(size_t)c * 1024 + k]);
}

// ---------------- compact hrel + fused root (p==16): 128x128 tiles, 1-product, BK=64 -------
__global__ __launch_bounds__(256) void hrelc_mfma(const unsigned short* __restrict__ xh,
                                                  const int* __restrict__ spRel,
                                                  const unsigned short* __restrict__ Wt,
                                                  const unsigned short* __restrict__ Rt,
                                                  const float* __restrict__ bias,
                                                  const int* __restrict__ pStart,
                                                  unsigned short* __restrict__ Hc,
                                                  unsigned short* __restrict__ xr) {
  __shared__ __align__(16) unsigned short As[128][72];
  __shared__ __align__(16) unsigned short Bs[128][72];
  const int tid = threadIdx.x;
  const int row0 = blockIdx.x * 128;
  const int sr0 = spRel[row0];
  if (sr0 < 0) return;
  const int p = sr0 & 31;
  const bool isRoot = (p == 16);
  const unsigned short* WHp = isRoot ? Rt : Wt + (size_t)p * 128 * 128;

  const int wid = tid >> 6, lane = tid & 63;
  const int rg = wid >> 1, cg = wid & 1;
  const int lr = lane & 15, lk = (lane >> 4) * 8;
  f4v acc[4][4] = {};

  // staging: chunk idx = tid + i*256 -> row/col = (tid>>3)+32i, k-offset = (tid&7)*8
  const int sr = tid >> 3, sc8 = (tid & 7) * 8;
  int arow[4];
#pragma unroll
  for (int i = 0; i < 4; ++i) {
    int v = spRel[row0 + sr + 32 * i];
    arow[i] = (v >= 0) ? (v >> 5) : -1;
  }
  s8v aR[4], bR[4];

  auto loadStep = [&](int k0) {
#pragma unroll
    for (int i = 0; i < 4; ++i) {
      if (arow[i] >= 0) aR[i] = *(const s8v*)&xh[(size_t)arow[i] * 128 + k0 + sc8];
      else { s8v zz = {0,0,0,0,0,0,0,0}; aR[i] = zz; }
      bR[i] = *(const s8v*)&WHp[(size_t)(sr + 32 * i) * 128 + k0 + sc8];
    }
  };
  auto writeStep = [&]() {
#pragma unroll
    for (int i = 0; i < 4; ++i) {
      *(s8v*)&As[sr + 32 * i][sc8] = aR[i];
      *(s8v*)&Bs[sr + 32 * i][sc8] = bR[i];
    }
  };

  loadStep(0);
  for (int k0 = 0; k0 < 128; k0 += 64) {
    __syncthreads();
    writeStep();
    __syncthreads();
    if (k0 == 0) loadStep(64);
#pragma unroll
    for (int ks = 0; ks < 2; ++ks) {
      s8v ah[4];
#pragma unroll
      for (int mf = 0; mf < 4; ++mf)
        ah[mf] = *(s8v*)&As[rg * 64 + mf * 16 + lr][ks * 32 + lk];
#pragma unroll
      for (int nf = 0; nf < 4; ++nf) {
        s8v bh_ = *(s8v*)&Bs[cg * 64 + nf * 16 + lr][ks * 32 + lk];
#pragma unroll
        for (int mf = 0; mf < 4; ++mf)
          acc[mf][nf] = __builtin_amdgcn_mfma_f32_16x16x32_bf16(ah[mf], bh_, acc[mf][nf], 0, 0, 0);
      }
    }
  }

  if (!isRoot) {
#pragma unroll
    for (int mf = 0; mf < 4; ++mf)
#pragma unroll
      for (int nf = 0; nf < 4; ++nf) {
        f4v v = acc[mf][nf];
        int rbase = row0 + rg * 64 + mf * 16 + (lane >> 4) * 4;
        int col = cg * 64 + nf * 16 + lr;
#pragma unroll
        for (int q = 0; q < 4; ++q)
          Hc[(size_t)(rbase + q) * 128 + col] = f2bf(v[q]);
      }
  } else {
    const int rootBase = pStart[RREL];
#pragma unroll
    for (int mf = 0; mf < 4; ++mf)
#pragma unroll
      for (int nf = 0; nf < 4; ++nf) {
        f4v v = acc[mf][nf];
        int rbase = row0 + rg * 64 + mf * 16 + (lane >> 4) * 4;
        int col = cg * 64 + nf * 16 + lr;
        float b = bias[col];
#pragma unroll
        for (int q = 0; q < 4; ++q) {
          int node = rbase + q - rootBase;
          if (node >= 0 && node < NN)
            xr[(size_t)node * 128 + col] = f2bf(v[q] + b);
        }
      }
  }
}

// ---------------- fused MLP layer-1 + head (parallel epilogue, LDS-atomic reduce) ----------
__global__ __launch_bounds__(256) void mlpcat_mfma(const unsigned short* __restrict__ xh,
                                                   const unsigned short* __restrict__ zh,
                                                   const unsigned short* __restrict__ ath,
                                                   const unsigned short* __restrict__ Wt,
                                                   const float* __restrict__ bcat,
                                                   const unsigned short* __restrict__ W2H,
                                                   const unsigned short* __restrict__ W2L,
                                                   float* __restrict__ logitsPart) {
  __shared__ __align__(16) char smem[25600];
  auto As = (unsigned short(*)[40])smem;            // 64 x 40 shorts = 5120 B
  auto Bs = (unsigned short(*)[40])(smem + 5120);   // 256 x 40 shorts = 20480 B
  const int tid = threadIdx.x;
  const int row0 = blockIdx.y * 64;
  const int cb = blockIdx.x;
  const int wid = tid >> 6, lane = tid & 63;
  const int wcol = wid * 64;
  const int lr = lane & 15, lk = (lane >> 4) * 8;
  f4v acc[4][4] = {};

  s8v aR;
  s8v bR[4];
  const int ar = tid >> 2, ac8 = (tid & 3) * 8;
  const int an = row0 + ar;

  auto loadStep = [&](int k0) {
    if (an < NN) {
      if (k0 < 128)      aR = *(const s8v*)&xh[(size_t)an * 128 + k0 + ac8];
      else if (k0 < 256) aR = *(const s8v*)&zh[(size_t)an * 128 + (k0 - 128) + ac8];
      else               aR = *(const s8v*)&ath[(size_t)an * 32 + (k0 - 256) + ac8];
    } else { s8v zz = {0, 0, 0, 0, 0, 0, 0, 0}; aR = zz; }
#pragma unroll
    for (int i = 0; i < 4; ++i) {
      int idx = tid + i * 256;
      int c = idx >> 2, c8 = (idx & 3) * 8;
      int gc = cb * 256 + c;
      bR[i] = *(const s8v*)&Wt[(size_t)gc * 288 + k0 + c8];
    }
  };
  auto writeStep = [&]() {
    *(s8v*)&As[ar][ac8] = aR;
#pragma unroll
    for (int i = 0; i < 4; ++i) {
      int idx = tid + i * 256;
      int c = idx >> 2, c8 = (idx & 3) * 8;
      *(s8v*)&Bs[c][c8] = bR[i];
    }
  };

  loadStep(0);
  for (int step = 0; step < 9; ++step) {
    __syncthreads();
    writeStep();
    __syncthreads();
    if (step < 8) loadStep((step + 1) * 32);

    s8v ah[4];
#pragma unroll
    for (int mf = 0; mf < 4; ++mf) ah[mf] = *(s8v*)&As[mf * 16 + lr][lk];
#pragma unroll
    for (int nf = 0; nf < 4; ++nf) {
      s8v bh_ = *(s8v*)&Bs[wcol + nf * 16 + lr][lk];
#pragma unroll
      for (int mf = 0; mf < 4; ++mf) {
        acc[mf][nf] = __builtin_amdgcn_mfma_f32_16x16x32_bf16(ah[mf], bh_, acc[mf][nf], 0, 0, 0);
      }
    }
  }

  // bias + relu in-register (this wave's 64x64 H sub-tile, cols wcol..wcol+63)
#pragma unroll
  for (int mf = 0; mf < 4; ++mf)
#pragma unroll
    for (int nf = 0; nf < 4; ++nf) {
      int gc = cb * 256 + wcol + nf * 16 + lr;
      float b = bcat[gc];
#pragma unroll
      for (int q = 0; q < 4; ++q)
        acc[mf][nf][q] = fmaxf(acc[mf][nf][q] + b, 0.f);
    }

  // ---- parallel epilogue: per-wave ht region + shared red via LDS atomics ----
  // ht[wid]: 64 x 34 shorts = 4352 B each (0..17408); red: 64 x 32 f32 = 8192 B (17408..25600)
  auto ht  = (unsigned short(*)[34])(smem + wid * 4352);
  auto red = (float(*)[32])(smem + 17408);
  __syncthreads();                       // As/Bs dead
  {
    float* rp = (float*)(smem + 17408);
#pragma unroll
    for (int i = 0; i < 8; ++i) rp[tid + i * 256] = 0.f;
  }
  __syncthreads();

  f4v acc2[4][2] = {};
#pragma unroll
  for (int ks = 0; ks < 2; ++ks) {
    // stage this wave's 64-row x 32-col bf16 slice (H cols wcol+ks*32 .. +31)
#pragma unroll
    for (int mf = 0; mf < 4; ++mf)
#pragma unroll
      for (int nfh = 0; nfh < 2; ++nfh) {
        int nf = ks * 2 + nfh;
#pragma unroll
        for (int q = 0; q < 4; ++q)
          ht[mf * 16 + (lane >> 4) * 4 + q][nfh * 16 + lr] = f2bf(acc[mf][nf][q]);
      }
    s8v a_[4];
#pragma unroll
    for (int mfp = 0; mfp < 4; ++mfp) a_[mfp] = *(s8v*)&ht[mfp * 16 + lr][lk];
    int kg = cb * 256 + wcol + ks * 32 + lk;
#pragma unroll
    for (int nfp = 0; nfp < 2; ++nfp) {
      int n = nfp * 16 + lr;
      s8v bh_ = *(const s8v*)&W2H[(size_t)n * 1024 + kg];
      s8v bl_ = *(const s8v*)&W2L[(size_t)n * 1024 + kg];
#pragma unroll
      for (int mfp = 0; mfp < 4; ++mfp) {
        acc2[mfp][nfp] = __builtin_amdgcn_mfma_f32_16x16x32_bf16(a_[mfp], bh_, acc2[mfp][nfp], 0, 0, 0);
        acc2[mfp][nfp] = __builtin_amdgcn_mfma_f32_16x16x32_bf16(a_[mfp], bl_, acc2[mfp][nfp], 0, 0, 0);
      }
    }
  }
#pragma unroll
  for (int mfp = 0; mfp < 4; ++mfp)
#pragma unroll
    for (int nfp = 0; nfp < 2; ++nfp)
#pragma unroll
      for (int q = 0; q < 4; ++q) {
        int node = mfp * 16 + (lane >> 4) * 4 + q;
        int L = nfp * 16 + lr;
        atomicAdd(&red[node][L], acc2[mfp][nfp][q]);
      }
  __syncthreads();
#pragma unroll
  for (int i = 0; i < 8; ++i) {
    int t = tid * 8 + i;                   // 0..2047
    int node = t >> 5, L = t & 31;
    int rr = row0 + node;
    if (rr < NN) logitsPart[((size_t)cb * NN + rr) * 32 + L] = red[node][L];
  }
}

// ---------------- head epilogue: sum 4 partials + biases + box copy + ang log_softmax -------
__global__ void head_post(const float* __restrict__ logitsPart, const float* __restrict__ box_b2,
                          const float* __restrict__ ang_b2, float* __restrict__ out) {
  int n = blockIdx.x * 256 + threadIdx.x;
  if (n >= NN) return;
  float l[32];
#pragma unroll
  for (int i = 0; i < 8; ++i)
    *(float4*)&l[i * 4] = *(const float4*)&logitsPart[(size_t)n * 32 + i * 4];
#pragma unroll
  for (int cb = 1; cb < 4; ++cb) {
#pragma unroll
    for (int i = 0; i < 8; ++i) {
      float4 v = *(const float4*)&logitsPart[((size_t)cb * NN + n) * 32 + i * 4];
      l[i * 4 + 0] += v.x; l[i * 4 + 1] += v.y;
      l[i * 4 + 2] += v.z; l[i * 4 + 3] += v.w;
    }
  }
  float* ob = out + (size_t)n * 6;
#pragma unroll
  for (int c = 0; c < 6; ++c) ob[c] = l[c] + box_b2[c];
  float a[24];
  float mx = -1e30f;
#pragma unroll
  for (int c = 0; c < 24; ++c) { a[c] = l[6 + c] + ang_b2[c]; mx = fmaxf(mx, a[c]); }
  float ssum = 0.f;
#pragma unroll
  for (int c = 0; c < 24; ++c) ssum += expf(a[c] - mx);
  float lse = mx + logf(ssum);
  float* oa = out + (size_t)NN * 6 + (size_t)n * 24;
#pragma unroll
  for (int c = 0; c < 24; ++c) oa[c] = a[c] - lse;
}

// ---------------- gather: xh[o] = relu( xr[o] + sum_e w * Hc[cid_e] ), 4-deep ILP ----------
__global__ __launch_bounds__(256) void gather_kernel(const unsigned short* __restrict__ Hc,
                                                     const int* __restrict__ binStart,
                                                     const int* __restrict__ offD,
                                                     const float* __restrict__ wD,
                                                     const unsigned short* __restrict__ xr,
                                                     unsigned short* __restrict__ xh) {
  int wid = threadIdx.x >> 6, lane = threadIdx.x & 63;
  int o = blockIdx.x * 4 + wid;
  if (o >= NN) return;
  int beg = binStart[o * RREL];
  int end = binStart[o * RREL + RREL];
  float a0 = 0.f, a1 = 0.f, b0 = 0.f, b1 = 0.f;
  float c0 = 0.f, c1 = 0.f, d0 = 0.f, d1 = 0.f;
  int i = beg;
  for (; i + 3 < end; i += 4) {
    int of1 = offD[i], of2 = offD[i + 1], of3 = offD[i + 2], of4 = offD[i + 3];
    float w1 = wD[i], w2 = wD[i + 1], w3 = wD[i + 2], w4 = wD[i + 3];
    unsigned int u1 = *(const unsigned int*)&Hc[of1 + lane * 2];
    unsigned int u2 = *(const unsigned int*)&Hc[of2 + lane * 2];
    unsigned int u3 = *(const unsigned int*)&Hc[of3 + lane * 2];
    unsigned int u4 = *(const unsigned int*)&Hc[of4 + lane * 2];
    a0 += w1 * bf2f(u1 & 0xffffu);
    a1 += w1 * bf2f(u1 >> 16);
    b0 += w2 * bf2f(u2 & 0xffffu);
    b1 += w2 * bf2f(u2 >> 16);
    c0 += w3 * bf2f(u3 & 0xffffu);
    c1 += w3 * bf2f(u3 >> 16);
    d0 += w4 * bf2f(u4 & 0xffffu);
    d1 += w4 * bf2f(u4 >> 16);
  }
  for (; i < end; ++i) {
    int of1 = offD[i];
    float w1 = wD[i];
    unsigned int u1 = *(const unsigned int*)&Hc[of1 + lane * 2];
    a0 += w1 * bf2f(u1 & 0xffffu);
    a1 += w1 * bf2f(u1 >> 16);
  }
  a0 += b0 + c0 + d0;
  a1 += b1 + c1 + d1;
  unsigned int ur = *(const unsigned int*)&xr[(size_t)o * 128 + lane * 2];
  float r0 = bf2f(ur & 0xffffu) + a0;
  float r1 = bf2f(ur >> 16) + a1;
  r0 = fmaxf(r0, 0.f); r1 = fmaxf(r1, 0.f);
  unsigned int pk = (unsigned int)f2bf(r0) | ((unsigned int)f2bf(r1) << 16);
  *(unsigned int*)&xh[(size_t)o * 128 + lane * 2] = pk;
}

// ------------------------------------------------------------------------
extern "C" void kernel_launch(void* const* d_in, const int* in_sizes, int n_in,
                              void* d_out, int out_size, void* d_ws, size_t ws_size,
                              hipStream_t stream) {
  const float* z        = (const float*)d_in[0];
  const int*   objs     = (const int*)d_in[1];
  const int*   triples  = (const int*)d_in[2];
  const int*   attrs    = (const int*)d_in[3];
  const float* obj_emb  = (const float*)d_in[4];
  const float* attr_emb = (const float*)d_in[5];
  const float* Wrel     = (const float*)d_in[6];
  const float* Wroot    = (const float*)d_in[7];
  const float* bconv    = (const float*)d_in[8];
  const float* box_W1   = (const float*)d_in[9];
  const float* box_b1   = (const float*)d_in[10];
  const float* box_W2   = (const float*)d_in[11];
  const float* box_b2   = (const float*)d_in[12];
  const float* ang_W1   = (const float*)d_in[13];
  const float* ang_b1   = (const float*)d_in[14];
  const float* ang_W2   = (const float*)d_in[15];
  const float* ang_b2   = (const float*)d_in[16];
  float* out = (float*)d_out;

  char* base = (char*)d_ws;
  size_t cur = 0;
  auto alloc = [&](size_t bytes) -> char* {
    char* p = base + cur;
    cur += (bytes + 255) & ~(size_t)255;
    return p;
  };
  unsigned short* Hc   = (unsigned short*)alloc((size_t)HCAP * 128 * 2);
  unsigned short* xr   = (unsigned short*)alloc((size_t)NN * 128 * 2);
  unsigned short* xhi  = (unsigned short*)alloc((size_t)NN * 128 * 2);
  unsigned short* zhi  = (unsigned short*)alloc((size_t)NN * 128 * 2);
  unsigned short* athi = (unsigned short*)alloc((size_t)NN * 32 * 2);
  unsigned short* WThi = (unsigned short*)alloc((size_t)LLAY * RREL * 128 * 128 * 2);
  unsigned short* WrtH = (unsigned short*)alloc((size_t)LLAY * 128 * 128 * 2);
  unsigned short* WcH  = (unsigned short*)alloc((size_t)1024 * 288 * 2);
  unsigned short* W2H  = (unsigned short*)alloc((size_t)32 * 1024 * 2);
  unsigned short* W2L  = (unsigned short*)alloc((size_t)32 * 1024 * 2);
  float* bcat          = (float*)alloc(1024 * 4);
  float* logitsPart    = (float*)alloc((size_t)4 * NN * 32 * 4);
  int*   cnt      = (int*)alloc((size_t)NBINS * 4);
  int*   binStart = (int*)alloc((size_t)(NBINS + 1) * 4);
  int*   cursor   = (int*)alloc((size_t)NBINS * 4);
  int*   sMark    = (int*)alloc((size_t)NBINS * 4);
  int*   spRel    = (int*)alloc((size_t)HCAP * 4);
  int*   partial  = (int*)alloc(4096);
  int*   meta     = (int*)alloc(256);      // Dp[16], pStart[18], pcur[16]
  int*   offD     = (int*)alloc((size_t)EE * 4);
  float* wD       = (float*)alloc((size_t)EE * 4);
  int* Dp = meta, *pStart = meta + 16, *pcur = meta + 40;

  hipMemsetAsync(cnt, 0, (size_t)NBINS * 4, stream);
  hipMemsetAsync(cursor, 0, (size_t)NBINS * 4, stream);
  hipMemsetAsync(sMark, 0, (size_t)NBINS * 4, stream);
  hipMemsetAsync(meta, 0, 256, stream);
  hipMemsetAsync(spRel, 0xFF, (size_t)HCAP * 4, stream);   // -1

  build_x0_kernel<<<(NN * 32 + 255) / 256, 256, 0, stream>>>(objs, attrs, obj_emb, attr_emb, xhi);
  prep_zattr<<<(NN * 40 + 255) / 256, 256, 0, stream>>>(z, attrs, attr_emb, zhi, athi);
  count_mark<<<(EE + 255) / 256, 256, 0, stream>>>(triples, cnt, sMark);
  const int nPart = (NBINS + 1023) / 1024;
  scanA<<<nPart, 1024, 0, stream>>>(cnt, binStart, partial);
  scanB<<<1, 1024, 0, stream>>>(partial, binStart, nPart);
  scanC<<<nPart, 1024, 0, stream>>>(binStart, partial);
  count_dp<<<(NBINS + 255) / 256, 256, 0, stream>>>(sMark, Dp);
  pad_scan<<<1, 64, 0, stream>>>(Dp, pStart);
  assign_cells<<<(NBINS + 255) / 256, 256, 0, stream>>>(sMark, pStart, pcur, spRel);
  fill_root<<<(NN + 255) / 256, 256, 0, stream>>>(pStart, spRel);
  place_kernel<<<(EE + 255) / 256, 256, 0, stream>>>(triples, cnt, binStart, cursor, sMark,
                                                     offD, wD);
  prep_wrel<<<(LLAY * RREL * 128 * 128 + 255) / 256, 256, 0, stream>>>(Wrel, WThi);
  prep_wroot<<<(LLAY * 128 * 128 + 255) / 256, 256, 0, stream>>>(Wroot, WrtH);
  prep_wcat<<<(1024 * 288 + 255) / 256, 256, 0, stream>>>(box_W1, ang_W1, WcH);
  prep_bcat<<<4, 256, 0, stream>>>(box_b1, ang_b1, bcat);
  prep_w2cat<<<(32 * 1024 + 255) / 256, 256, 0, stream>>>(box_W2, ang_W2, W2H, W2L);

  const int rowBlocks = (NN + 63) / 64;      // 782
  for (int j = 0; j < LLAY; ++j) {
    hrelc_mfma<<<HCAP / 128, 256, 0, stream>>>(xhi, spRel,
                                               WThi + (size_t)j * RREL * 128 * 128,
                                               WrtH + (size_t)j * 128 * 128,
                                               bconv + (size_t)j * 128, pStart, Hc, xr);
    gather_kernel<<<(NN + 3) / 4, 256, 0, stream>>>(Hc, binStart, offD, wD, xr, xhi);
  }

  mlpcat_mfma<<<dim3(4, rowBlocks), 256, 0, stream>>>(xhi, zhi, athi, WcH, bcat,
                                                      W2H, W2L, logitsPart);
  head_post<<<(NN + 255) / 256, 256, 0, stream>>>(logitsPart, box_b2, ang_b2, out);
}

// Round 17
// 847.379 us; speedup vs baseline: 1.1241x; 1.1241x over previous
//
#include <hip/hip_runtime.h>
#include <hip/hip_bf16.h>
#include <math.h>

#define NN   50000
#define EE   800000
#define RREL 16
#define LLAY 5
#define NBINS (NN * RREL)
#define HCAP 565248   // compact rows: ~506k rel cells + pad + 50048 root rows

typedef __attribute__((ext_vector_type(8))) short s8v;
typedef __attribute__((ext_vector_type(4))) float f4v;

__device__ __forceinline__ unsigned short f2bf(float f) {
  __hip_bfloat16 h = __float2bfloat16(f);
  return __builtin_bit_cast(unsigned short, h);
}
__device__ __forceinline__ float bf2f(unsigned int u) {
  return __builtin_bit_cast(float, u << 16);
}
__device__ __forceinline__ void split1(float v, unsigned short& h, unsigned short& l) {
  __hip_bfloat16 hb = __float2bfloat16(v);
  float hf = __bfloat162float(hb);
  h = __builtin_bit_cast(unsigned short, hb);
  __hip_bfloat16 lb = __float2bfloat16(v - hf);
  l = __builtin_bit_cast(unsigned short, lb);
}

// ---------------- build xh0 = bf16([obj_emb[objs] | attr_emb[attributes]]) ----------------
__global__ void build_x0_kernel(const int* __restrict__ objs, const int* __restrict__ attrs,
                                const float* __restrict__ obj_emb, const float* __restrict__ attr_emb,
                                unsigned short* __restrict__ xh) {
  int t = blockIdx.x * blockDim.x + threadIdx.x;
  if (t >= NN * 32) return;
  int n = t >> 5, q = t & 31;
  float4 v;
  if (q < 24) v = *(const float4*)&obj_emb[(size_t)objs[n] * 96 + q * 4];
  else        v = *(const float4*)&attr_emb[(size_t)attrs[n] * 32 + (q - 24) * 4];
  ushort4 h;
  h.x = f2bf(v.x); h.y = f2bf(v.y); h.z = f2bf(v.z); h.w = f2bf(v.w);
  *(ushort4*)&xh[(size_t)n * 128 + q * 4] = h;
}

// ---------------- bf16-convert z (N,128) and attr_emb[attrs] (N,32) ----------------
__global__ void prep_zattr(const float* __restrict__ z, const int* __restrict__ attrs,
                           const float* __restrict__ attr_emb,
                           unsigned short* __restrict__ zh, unsigned short* __restrict__ ah) {
  int t = blockIdx.x * blockDim.x + threadIdx.x;
  if (t >= NN * 40) return;
  int n = t / 40, q = t % 40;
  float4 v;
  ushort4 h;
  if (q < 32) {
    v = *(const float4*)&z[(size_t)n * 128 + q * 4];
    h.x = f2bf(v.x); h.y = f2bf(v.y); h.z = f2bf(v.z); h.w = f2bf(v.w);
    *(ushort4*)&zh[(size_t)n * 128 + q * 4] = h;
  } else {
    int qq = q - 32;
    v = *(const float4*)&attr_emb[(size_t)attrs[n] * 32 + qq * 4];
    h.x = f2bf(v.x); h.y = f2bf(v.y); h.z = f2bf(v.z); h.w = f2bf(v.w);
    *(ushort4*)&ah[(size_t)n * 32 + qq * 4] = h;
  }
}

// ---------------- fused (o,p) count + (s,p) mark ----------------
__global__ void count_mark(const int* __restrict__ triples, int* __restrict__ cnt,
                           int* __restrict__ sMark) {
  int e = blockIdx.x * 256 + threadIdx.x;
  if (e >= EE) return;
  int s = triples[e * 3 + 0], p = triples[e * 3 + 1], o = triples[e * 3 + 2];
  atomicAdd(&cnt[o * RREL + p], 1);
  atomicAdd(&sMark[s * RREL + p], 1);
}
__global__ void scanA(const int* __restrict__ cnt, int* __restrict__ binStart,
                      int* __restrict__ partial) {
  __shared__ int buf[1024];
  int g = blockIdx.x * 1024 + threadIdx.x;
  int v = (g < NBINS) ? cnt[g] : 0;
  buf[threadIdx.x] = v;
  __syncthreads();
  for (int d = 1; d < 1024; d <<= 1) {
    int t = (threadIdx.x >= d) ? buf[threadIdx.x - d] : 0;
    __syncthreads();
    buf[threadIdx.x] += t;
    __syncthreads();
  }
  if (g < NBINS) binStart[g] = buf[threadIdx.x] - v;
  if (threadIdx.x == 1023) partial[blockIdx.x] = buf[1023];
}
__global__ void scanB(int* __restrict__ partial, int* __restrict__ binStart, int nPart) {
  __shared__ int buf[1024];
  int v = (threadIdx.x < nPart) ? partial[threadIdx.x] : 0;
  buf[threadIdx.x] = v;
  __syncthreads();
  for (int d = 1; d < 1024; d <<= 1) {
    int t = (threadIdx.x >= d) ? buf[threadIdx.x - d] : 0;
    __syncthreads();
    buf[threadIdx.x] += t;
    __syncthreads();
  }
  if (threadIdx.x < nPart) partial[threadIdx.x] = buf[threadIdx.x] - v;
  if (threadIdx.x == 1023) binStart[NBINS] = buf[1023];
}
__global__ void scanC(int* __restrict__ binStart, const int* __restrict__ partial) {
  int g = blockIdx.x * 1024 + threadIdx.x;
  if (g < NBINS) binStart[g] += partial[blockIdx.x];
}

// ---------------- (s,p) compaction ----------------
__global__ void count_dp(const int* __restrict__ sMark, int* __restrict__ Dp) {
  __shared__ int lh[RREL];
  if (threadIdx.x < RREL) lh[threadIdx.x] = 0;
  __syncthreads();
  int c = blockIdx.x * 256 + threadIdx.x;
  if (c < NBINS && sMark[c] > 0) atomicAdd(&lh[c & 15], 1);
  __syncthreads();
  if (threadIdx.x < RREL && lh[threadIdx.x] > 0)
    atomicAdd(&Dp[threadIdx.x], lh[threadIdx.x]);
}
// pStart[0..16] = 16 relation partitions + root partition (NN rows); pStart[17] = total
__global__ void pad_scan(const int* __restrict__ Dp, int* __restrict__ pStart) {
  if (threadIdx.x == 0 && blockIdx.x == 0) {
    int s = 0;
    for (int p = 0; p < RREL; ++p) {
      pStart[p] = s;
      s += ((Dp[p] + 127) >> 7) << 7;
    }
    pStart[RREL] = s;                       // root partition base
    s += ((NN + 127) >> 7) << 7;
    pStart[RREL + 1] = s;
  }
}
// spRel[cid] = s*32 + p  (p in 0..15 relation cell, p==16 root row)
__global__ void assign_cells(int* __restrict__ sMark, const int* __restrict__ pStart,
                             int* __restrict__ pcur, int* __restrict__ spRel) {
  __shared__ int lh[RREL], lbase[RREL];
  if (threadIdx.x < RREL) lh[threadIdx.x] = 0;
  __syncthreads();
  int c = blockIdx.x * 256 + threadIdx.x;
  bool occ = (c < NBINS) && (sMark[c] > 0);
  int p = 0, my = 0;
  if (occ) { p = c & 15; my = atomicAdd(&lh[p], 1); }
  __syncthreads();
  if (threadIdx.x < RREL)
    lbase[threadIdx.x] = (lh[threadIdx.x] > 0)
                           ? atomicAdd(&pcur[threadIdx.x], lh[threadIdx.x]) : 0;
  __syncthreads();
  if (occ) {
    int cid = pStart[p] + lbase[p] + my;
    if (cid < HCAP) spRel[cid] = (c >> 4) * 32 + p;
    sMark[c] = cid + 1;
  }
}
__global__ void fill_root(const int* __restrict__ pStart, int* __restrict__ spRel) {
  int n = blockIdx.x * 256 + threadIdx.x;
  if (n >= NN) return;
  int cid = pStart[RREL] + n;
  if (cid < HCAP) spRel[cid] = n * 32 + 16;
}
// offD = cid*128 (element offset into compact H); wD = 1/deg(o,p)
__global__ void place_kernel(const int* __restrict__ triples, const int* __restrict__ cnt,
                             const int* __restrict__ binStart, int* __restrict__ cursor,
                             const int* __restrict__ sMark,
                             int* __restrict__ offD, float* __restrict__ wD) {
  int e = blockIdx.x * 256 + threadIdx.x;
  if (e >= EE) return;
  int s = triples[e * 3 + 0], p = triples[e * 3 + 1], o = triples[e * 3 + 2];
  int bin = o * RREL + p;
  int pos = binStart[bin] + atomicAdd(&cursor[bin], 1);
  int cid = sMark[s * RREL + p] - 1;
  offD[pos] = cid * 128;
  wD[pos] = 1.0f / (float)cnt[bin];
}

// ---------------- weight preps ----------------
__global__ void prep_wrel(const float* __restrict__ Wrel, unsigned short* __restrict__ WT) {
  int t = blockIdx.x * 256 + threadIdx.x;
  if (t >= LLAY * RREL * 128 * 128) return;
  int f = t & 127, k = (t >> 7) & 127, lr = t >> 14;
  float v = Wrel[((size_t)lr * 128 + k) * 128 + f];
  WT[((size_t)lr * 128 + f) * 128 + k] = f2bf(v);
}
__global__ void prep_wroot(const float* __restrict__ Wroot, unsigned short* __restrict__ WT) {
  int t = blockIdx.x * 256 + threadIdx.x;
  if (t >= LLAY * 128 * 128) return;
  int f = t & 127, k = (t >> 7) & 127, l = t >> 14;
  float v = Wroot[((size_t)l * 128 + k) * 128 + f];
  WT[((size_t)l * 128 + f) * 128 + k] = f2bf(v);
}
__global__ void prep_wcat(const float* __restrict__ box_W1, const float* __restrict__ ang_W1,
                          unsigned short* __restrict__ WT) {
  int t = blockIdx.x * 256 + threadIdx.x;
  if (t >= 1024 * 288) return;
  int k = t % 288, c = t / 288;
  float v;
  if (c < 512) v = box_W1[(size_t)k * 512 + c];
  else         v = (k < 256) ? ang_W1[(size_t)k * 512 + (c - 512)] : 0.f;
  WT[(size_t)c * 288 + k] = f2bf(v);
}
__global__ void prep_bcat(const float* __restrict__ box_b1, const float* __restrict__ ang_b1,
                          float* __restrict__ bcat) {
  int t = blockIdx.x * 256 + threadIdx.x;
  if (t >= 1024) return;
  bcat[t] = (t < 512) ? box_b1[t] : ang_b1[t - 512];
}
__global__ void prep_w2cat(const float* __restrict__ box_W2, const float* __restrict__ ang_W2,
                           unsigned short* __restrict__ hi, unsigned short* __restrict__ lo) {
  int t = blockIdx.x * 256 + threadIdx.x;
  if (t >= 32 * 1024) return;
  int k = t & 1023, c = t >> 10;
  float v = 0.f;
  if (c < 6)       { if (k < 512)  v = box_W2[(size_t)k * 6 + c]; }
  else if (c < 30) { if (k >= 512) v = ang_W2[(size_t)(k - 512) * 24 + (c - 6)]; }
  split1(v, hi[(size_t)c * 1024 + k], lo[(size_t)c * 1024 + k]);
}

// ---------------- compact hrel + fused root (p==16): 128x128 tiles, 1-product, BK=64 -------
__global__ __launch_bounds__(256) void hrelc_mfma(const unsigned short* __restrict__ xh,
                                                  const int* __restrict__ spRel,
                                                  const unsigned short* __restrict__ Wt,
                                                  const unsigned short* __restrict__ Rt,
                                                  const float* __restrict__ bias,
                                                  const int* __restrict__ pStart,
                                                  unsigned short* __restrict__ Hc,
                                                  unsigned short* __restrict__ xr) {
  __shared__ __align__(16) unsigned short As[128][72];
  __shared__ __align__(16) unsigned short Bs[128][72];
  const int tid = threadIdx.x;
  const int row0 = blockIdx.x * 128;
  const int sr0 = spRel[row0];
  if (sr0 < 0) return;
  const int p = sr0 & 31;
  const bool isRoot = (p == 16);
  const unsigned short* WHp = isRoot ? Rt : Wt + (size_t)p * 128 * 128;

  const int wid = tid >> 6, lane = tid & 63;
  const int rg = wid >> 1, cg = wid & 1;
  const int lr = lane & 15, lk = (lane >> 4) * 8;
  f4v acc[4][4] = {};

  const int sr = tid >> 3, sc8 = (tid & 7) * 8;
  int arow[4];
#pragma unroll
  for (int i = 0; i < 4; ++i) {
    int v = spRel[row0 + sr + 32 * i];
    arow[i] = (v >= 0) ? (v >> 5) : -1;
  }
  s8v aR[4], bR[4];

  auto loadStep = [&](int k0) {
#pragma unroll
    for (int i = 0; i < 4; ++i) {
      if (arow[i] >= 0) aR[i] = *(const s8v*)&xh[(size_t)arow[i] * 128 + k0 + sc8];
      else { s8v zz = {0,0,0,0,0,0,0,0}; aR[i] = zz; }
      bR[i] = *(const s8v*)&WHp[(size_t)(sr + 32 * i) * 128 + k0 + sc8];
    }
  };
  auto writeStep = [&]() {
#pragma unroll
    for (int i = 0; i < 4; ++i) {
      *(s8v*)&As[sr + 32 * i][sc8] = aR[i];
      *(s8v*)&Bs[sr + 32 * i][sc8] = bR[i];
    }
  };

  loadStep(0);
  for (int k0 = 0; k0 < 128; k0 += 64) {
    __syncthreads();
    writeStep();
    __syncthreads();
    if (k0 == 0) loadStep(64);
#pragma unroll
    for (int ks = 0; ks < 2; ++ks) {
      s8v ah[4];
#pragma unroll
      for (int mf = 0; mf < 4; ++mf)
        ah[mf] = *(s8v*)&As[rg * 64 + mf * 16 + lr][ks * 32 + lk];
#pragma unroll
      for (int nf = 0; nf < 4; ++nf) {
        s8v bh_ = *(s8v*)&Bs[cg * 64 + nf * 16 + lr][ks * 32 + lk];
#pragma unroll
        for (int mf = 0; mf < 4; ++mf)
          acc[mf][nf] = __builtin_amdgcn_mfma_f32_16x16x32_bf16(ah[mf], bh_, acc[mf][nf], 0, 0, 0);
      }
    }
  }

  if (!isRoot) {
#pragma unroll
    for (int mf = 0; mf < 4; ++mf)
#pragma unroll
      for (int nf = 0; nf < 4; ++nf) {
        f4v v = acc[mf][nf];
        int rbase = row0 + rg * 64 + mf * 16 + (lane >> 4) * 4;
        int col = cg * 64 + nf * 16 + lr;
#pragma unroll
        for (int q = 0; q < 4; ++q)
          Hc[(size_t)(rbase + q) * 128 + col] = f2bf(v[q]);
      }
  } else {
    const int rootBase = pStart[RREL];
#pragma unroll
    for (int mf = 0; mf < 4; ++mf)
#pragma unroll
      for (int nf = 0; nf < 4; ++nf) {
        f4v v = acc[mf][nf];
        int rbase = row0 + rg * 64 + mf * 16 + (lane >> 4) * 4;
        int col = cg * 64 + nf * 16 + lr;
        float b = bias[col];
#pragma unroll
        for (int q = 0; q < 4; ++q) {
          int node = rbase + q - rootBase;
          if (node >= 0 && node < NN)
            xr[(size_t)node * 128 + col] = f2bf(v[q] + b);
        }
      }
  }
}

// ---------------- fused MLP layer-1 + head (serialized epilogue, 16B-aligned ht) -----------
__global__ __launch_bounds__(256) void mlpcat_mfma(const unsigned short* __restrict__ xh,
                                                   const unsigned short* __restrict__ zh,
                                                   const unsigned short* __restrict__ ath,
                                                   const unsigned short* __restrict__ Wt,
                                                   const float* __restrict__ bcat,
                                                   const unsigned short* __restrict__ W2H,
                                                   const unsigned short* __restrict__ W2L,
                                                   float* __restrict__ logitsPart) {
  __shared__ __align__(16) char smem[25600];
  auto As = (unsigned short(*)[40])smem;            // 64 x 40 shorts = 5120 B
  auto Bs = (unsigned short(*)[40])(smem + 5120);   // 256 x 40 shorts = 20480 B
  auto ht = (unsigned short(*)[80])smem;            // epilogue: 64 x 80 shorts = 10240 B
  auto red = (float(*)[33])(smem + 10240);          // epilogue: 64 x 33 f32 = 8448 B
  const int tid = threadIdx.x;
  const int row0 = blockIdx.y * 64;
  const int cb = blockIdx.x;
  const int wid = tid >> 6, lane = tid & 63;
  const int wcol = wid * 64;
  const int lr = lane & 15, lk = (lane >> 4) * 8;
  f4v acc[4][4] = {};

  s8v aR;
  s8v bR[4];
  const int ar = tid >> 2, ac8 = (tid & 3) * 8;
  const int an = row0 + ar;

  auto loadStep = [&](int k0) {
    if (an < NN) {
      if (k0 < 128)      aR = *(const s8v*)&xh[(size_t)an * 128 + k0 + ac8];
      else if (k0 < 256) aR = *(const s8v*)&zh[(size_t)an * 128 + (k0 - 128) + ac8];
      else               aR = *(const s8v*)&ath[(size_t)an * 32 + (k0 - 256) + ac8];
    } else { s8v zz = {0, 0, 0, 0, 0, 0, 0, 0}; aR = zz; }
#pragma unroll
    for (int i = 0; i < 4; ++i) {
      int idx = tid + i * 256;
      int c = idx >> 2, c8 = (idx & 3) * 8;
      int gc = cb * 256 + c;
      bR[i] = *(const s8v*)&Wt[(size_t)gc * 288 + k0 + c8];
    }
  };
  auto writeStep = [&]() {
    *(s8v*)&As[ar][ac8] = aR;
#pragma unroll
    for (int i = 0; i < 4; ++i) {
      int idx = tid + i * 256;
      int c = idx >> 2, c8 = (idx & 3) * 8;
      *(s8v*)&Bs[c][c8] = bR[i];
    }
  };

  loadStep(0);
  for (int step = 0; step < 9; ++step) {
    __syncthreads();
    writeStep();
    __syncthreads();
    if (step < 8) loadStep((step + 1) * 32);

    s8v ah[4];
#pragma unroll
    for (int mf = 0; mf < 4; ++mf) ah[mf] = *(s8v*)&As[mf * 16 + lr][lk];
#pragma unroll
    for (int nf = 0; nf < 4; ++nf) {
      s8v bh_ = *(s8v*)&Bs[wcol + nf * 16 + lr][lk];
#pragma unroll
      for (int mf = 0; mf < 4; ++mf) {
        acc[mf][nf] = __builtin_amdgcn_mfma_f32_16x16x32_bf16(ah[mf], bh_, acc[mf][nf], 0, 0, 0);
      }
    }
  }

  // bias + relu in-register (this wave's 64x64 H sub-tile, cols wcol..wcol+63)
#pragma unroll
  for (int mf = 0; mf < 4; ++mf)
#pragma unroll
    for (int nf = 0; nf < 4; ++nf) {
      int gc = cb * 256 + wcol + nf * 16 + lr;
      float b = bcat[gc];
#pragma unroll
      for (int q = 0; q < 4; ++q)
        acc[mf][nf][q] = fmaxf(acc[mf][nf][q] + b, 0.f);
    }

  // epilogue: per-wave partial logits over its 64-wide k-slice, reduced in LDS
  for (int w = 0; w < 4; ++w) {
    __syncthreads();
    if (wid == w) {
#pragma unroll
      for (int mf = 0; mf < 4; ++mf)
#pragma unroll
        for (int nf = 0; nf < 4; ++nf)
#pragma unroll
          for (int q = 0; q < 4; ++q)
            ht[mf * 16 + (lane >> 4) * 4 + q][nf * 16 + lr] = f2bf(acc[mf][nf][q]);

      f4v acc2[4][2] = {};
#pragma unroll
      for (int ks = 0; ks < 2; ++ks) {
        s8v a_[4];
#pragma unroll
        for (int mfp = 0; mfp < 4; ++mfp)
          a_[mfp] = *(s8v*)&ht[mfp * 16 + lr][ks * 32 + lk];
#pragma unroll
        for (int nfp = 0; nfp < 2; ++nfp) {
          int kg = cb * 256 + wcol + ks * 32 + lk;
          int n = nfp * 16 + lr;
          s8v bh_ = *(const s8v*)&W2H[(size_t)n * 1024 + kg];
          s8v bl_ = *(const s8v*)&W2L[(size_t)n * 1024 + kg];
#pragma unroll
          for (int mfp = 0; mfp < 4; ++mfp) {
            acc2[mfp][nfp] = __builtin_amdgcn_mfma_f32_16x16x32_bf16(a_[mfp], bh_, acc2[mfp][nfp], 0, 0, 0);
            acc2[mfp][nfp] = __builtin_amdgcn_mfma_f32_16x16x32_bf16(a_[mfp], bl_, acc2[mfp][nfp], 0, 0, 0);
          }
        }
      }
#pragma unroll
      for (int mfp = 0; mfp < 4; ++mfp)
#pragma unroll
        for (int nfp = 0; nfp < 2; ++nfp)
#pragma unroll
          for (int q = 0; q < 4; ++q) {
            int node = mfp * 16 + (lane >> 4) * 4 + q;
            int L = nfp * 16 + lr;
            if (w == 0) red[node][L] = acc2[mfp][nfp][q];
            else        red[node][L] += acc2[mfp][nfp][q];
          }
    }
  }
  __syncthreads();
#pragma unroll
  for (int i = 0; i < 8; ++i) {
    int t = tid * 8 + i;                   // 0..2047
    int node = t >> 5, L = t & 31;
    int rr = row0 + node;
    if (rr < NN) logitsPart[((size_t)cb * NN + rr) * 32 + L] = red[node][L];
  }
}

// ---------------- head epilogue: sum 4 partials + biases + box copy + ang log_softmax -------
__global__ void head_post(const float* __restrict__ logitsPart, const float* __restrict__ box_b2,
                          const float* __restrict__ ang_b2, float* __restrict__ out) {
  int n = blockIdx.x * 256 + threadIdx.x;
  if (n >= NN) return;
  float l[32];
#pragma unroll
  for (int i = 0; i < 8; ++i)
    *(float4*)&l[i * 4] = *(const float4*)&logitsPart[(size_t)n * 32 + i * 4];
#pragma unroll
  for (int cb = 1; cb < 4; ++cb) {
#pragma unroll
    for (int i = 0; i < 8; ++i) {
      float4 v = *(const float4*)&logitsPart[((size_t)cb * NN + n) * 32 + i * 4];
      l[i * 4 + 0] += v.x; l[i * 4 + 1] += v.y;
      l[i * 4 + 2] += v.z; l[i * 4 + 3] += v.w;
    }
  }
  float* ob = out + (size_t)n * 6;
#pragma unroll
  for (int c = 0; c < 6; ++c) ob[c] = l[c] + box_b2[c];
  float a[24];
  float mx = -1e30f;
#pragma unroll
  for (int c = 0; c < 24; ++c) { a[c] = l[6 + c] + ang_b2[c]; mx = fmaxf(mx, a[c]); }
  float ssum = 0.f;
#pragma unroll
  for (int c = 0; c < 24; ++c) ssum += expf(a[c] - mx);
  float lse = mx + logf(ssum);
  float* oa = out + (size_t)NN * 6 + (size_t)n * 24;
#pragma unroll
  for (int c = 0; c < 24; ++c) oa[c] = a[c] - lse;
}

// ---------------- gather: xh[o] = relu( xr[o] + sum_e w * Hc[cid_e] ), 4-deep ILP ----------
__global__ __launch_bounds__(256) void gather_kernel(const unsigned short* __restrict__ Hc,
                                                     const int* __restrict__ binStart,
                                                     const int* __restrict__ offD,
                                                     const float* __restrict__ wD,
                                                     const unsigned short* __restrict__ xr,
                                                     unsigned short* __restrict__ xh) {
  int wid = threadIdx.x >> 6, lane = threadIdx.x & 63;
  int o = blockIdx.x * 4 + wid;
  if (o >= NN) return;
  int beg = binStart[o * RREL];
  int end = binStart[o * RREL + RREL];
  float a0 = 0.f, a1 = 0.f, b0 = 0.f, b1 = 0.f;
  float c0 = 0.f, c1 = 0.f, d0 = 0.f, d1 = 0.f;
  int i = beg;
  for (; i + 3 < end; i += 4) {
    int of1 = offD[i], of2 = offD[i + 1], of3 = offD[i + 2], of4 = offD[i + 3];
    float w1 = wD[i], w2 = wD[i + 1], w3 = wD[i + 2], w4 = wD[i + 3];
    unsigned int u1 = *(const unsigned int*)&Hc[of1 + lane * 2];
    unsigned int u2 = *(const unsigned int*)&Hc[of2 + lane * 2];
    unsigned int u3 = *(const unsigned int*)&Hc[of3 + lane * 2];
    unsigned int u4 = *(const unsigned int*)&Hc[of4 + lane * 2];
    a0 += w1 * bf2f(u1 & 0xffffu);
    a1 += w1 * bf2f(u1 >> 16);
    b0 += w2 * bf2f(u2 & 0xffffu);
    b1 += w2 * bf2f(u2 >> 16);
    c0 += w3 * bf2f(u3 & 0xffffu);
    c1 += w3 * bf2f(u3 >> 16);
    d0 += w4 * bf2f(u4 & 0xffffu);
    d1 += w4 * bf2f(u4 >> 16);
  }
  for (; i < end; ++i) {
    int of1 = offD[i];
    float w1 = wD[i];
    unsigned int u1 = *(const unsigned int*)&Hc[of1 + lane * 2];
    a0 += w1 * bf2f(u1 & 0xffffu);
    a1 += w1 * bf2f(u1 >> 16);
  }
  a0 += b0 + c0 + d0;
  a1 += b1 + c1 + d1;
  unsigned int ur = *(const unsigned int*)&xr[(size_t)o * 128 + lane * 2];
  float r0 = bf2f(ur & 0xffffu) + a0;
  float r1 = bf2f(ur >> 16) + a1;
  r0 = fmaxf(r0, 0.f); r1 = fmaxf(r1, 0.f);
  unsigned int pk = (unsigned int)f2bf(r0) | ((unsigned int)f2bf(r1) << 16);
  *(unsigned int*)&xh[(size_t)o * 128 + lane * 2] = pk;
}

// ------------------------------------------------------------------------
extern "C" void kernel_launch(void* const* d_in, const int* in_sizes, int n_in,
                              void* d_out, int out_size, void* d_ws, size_t ws_size,
                              hipStream_t stream) {
  const float* z        = (const float*)d_in[0];
  const int*   objs     = (const int*)d_in[1];
  const int*   triples  = (const int*)d_in[2];
  const int*   attrs    = (const int*)d_in[3];
  const float* obj_emb  = (const float*)d_in[4];
  const float* attr_emb = (const float*)d_in[5];
  const float* Wrel     = (const float*)d_in[6];
  const float* Wroot    = (const float*)d_in[7];
  const float* bconv    = (const float*)d_in[8];
  const float* box_W1   = (const float*)d_in[9];
  const float* box_b1   = (const float*)d_in[10];
  const float* box_W2   = (const float*)d_in[11];
  const float* box_b2   = (const float*)d_in[12];
  const float* ang_W1   = (const float*)d_in[13];
  const float* ang_b1   = (const float*)d_in[14];
  const float* ang_W2   = (const float*)d_in[15];
  const float* ang_b2   = (const float*)d_in[16];
  float* out = (float*)d_out;

  char* base = (char*)d_ws;
  size_t cur = 0;
  auto alloc = [&](size_t bytes) -> char* {
    char* p = base + cur;
    cur += (bytes + 255) & ~(size_t)255;
    return p;
  };
  unsigned short* Hc   = (unsigned short*)alloc((size_t)HCAP * 128 * 2);
  unsigned short* xr   = (unsigned short*)alloc((size_t)NN * 128 * 2);
  unsigned short* xhi  = (unsigned short*)alloc((size_t)NN * 128 * 2);
  unsigned short* zhi  = (unsigned short*)alloc((size_t)NN * 128 * 2);
  unsigned short* athi = (unsigned short*)alloc((size_t)NN * 32 * 2);
  unsigned short* WThi = (unsigned short*)alloc((size_t)LLAY * RREL * 128 * 128 * 2);
  unsigned short* WrtH = (unsigned short*)alloc((size_t)LLAY * 128 * 128 * 2);
  unsigned short* WcH  = (unsigned short*)alloc((size_t)1024 * 288 * 2);
  unsigned short* W2H  = (unsigned short*)alloc((size_t)32 * 1024 * 2);
  unsigned short* W2L  = (unsigned short*)alloc((size_t)32 * 1024 * 2);
  float* bcat          = (float*)alloc(1024 * 4);
  float* logitsPart    = (float*)alloc((size_t)4 * NN * 32 * 4);
  int*   cnt      = (int*)alloc((size_t)NBINS * 4);
  int*   binStart = (int*)alloc((size_t)(NBINS + 1) * 4);
  int*   cursor   = (int*)alloc((size_t)NBINS * 4);
  int*   sMark    = (int*)alloc((size_t)NBINS * 4);
  int*   spRel    = (int*)alloc((size_t)HCAP * 4);
  int*   partial  = (int*)alloc(4096);
  int*   meta     = (int*)alloc(256);      // Dp[16], pStart[18], pcur[16]
  int*   offD     = (int*)alloc((size_t)EE * 4);
  float* wD       = (float*)alloc((size_t)EE * 4);
  int* Dp = meta, *pStart = meta + 16, *pcur = meta + 40;

  hipMemsetAsync(cnt, 0, (size_t)NBINS * 4, stream);
  hipMemsetAsync(cursor, 0, (size_t)NBINS * 4, stream);
  hipMemsetAsync(sMark, 0, (size_t)NBINS * 4, stream);
  hipMemsetAsync(meta, 0, 256, stream);
  hipMemsetAsync(spRel, 0xFF, (size_t)HCAP * 4, stream);   // -1

  build_x0_kernel<<<(NN * 32 + 255) / 256, 256, 0, stream>>>(objs, attrs, obj_emb, attr_emb, xhi);
  prep_zattr<<<(NN * 40 + 255) / 256, 256, 0, stream>>>(z, attrs, attr_emb, zhi, athi);
  count_mark<<<(EE + 255) / 256, 256, 0, stream>>>(triples, cnt, sMark);
  const int nPart = (NBINS + 1023) / 1024;
  scanA<<<nPart, 1024, 0, stream>>>(cnt, binStart, partial);
  scanB<<<1, 1024, 0, stream>>>(partial, binStart, nPart);
  scanC<<<nPart, 1024, 0, stream>>>(binStart, partial);
  count_dp<<<(NBINS + 255) / 256, 256, 0, stream>>>(sMark, Dp);
  pad_scan<<<1, 64, 0, stream>>>(Dp, pStart);
  assign_cells<<<(NBINS + 255) / 256, 256, 0, stream>>>(sMark, pStart, pcur, spRel);
  fill_root<<<(NN + 255) / 256, 256, 0, stream>>>(pStart, spRel);
  place_kernel<<<(EE + 255) / 256, 256, 0, stream>>>(triples, cnt, binStart, cursor, sMark,
                                                     offD, wD);
  prep_wrel<<<(LLAY * RREL * 128 * 128 + 255) / 256, 256, 0, stream>>>(Wrel, WThi);
  prep_wroot<<<(LLAY * 128 * 128 + 255) / 256, 256, 0, stream>>>(Wroot, WrtH);
  prep_wcat<<<(1024 * 288 + 255) / 256, 256, 0, stream>>>(box_W1, ang_W1, WcH);
  prep_bcat<<<4, 256, 0, stream>>>(box_b1, ang_b1, bcat);
  prep_w2cat<<<(32 * 1024 + 255) / 256, 256, 0, stream>>>(box_W2, ang_W2, W2H, W2L);

  const int rowBlocks = (NN + 63) / 64;      // 782
  for (int j = 0; j < LLAY; ++j) {
    hrelc_mfma<<<HCAP / 128, 256, 0, stream>>>(xhi, spRel,
                                               WThi + (size_t)j * RREL * 128 * 128,
                                               WrtH + (size_t)j * 128 * 128,
                                               bconv + (size_t)j * 128, pStart, Hc, xr);
    gather_kernel<<<(NN + 3) / 4, 256, 0, stream>>>(Hc, binStart, offD, wD, xr, xhi);
  }

  mlpcat_mfma<<<dim3(4, rowBlocks), 256, 0, stream>>>(xhi, zhi, athi, WcH, bcat,
                                                      W2H, W2L, logitsPart);
  head_post<<<(NN + 255) / 256, 256, 0, stream>>>(logitsPart, box_b2, ang_b2, out);
}